// Round 11
// baseline (2319.465 us; speedup 1.0000x reference)
//
#include <hip/hip_runtime.h>
#include <math.h>

#define BB 16
#define LL 128
#define HH 1024
#define EE 512
#define VV 32000
#define G3 3072
#define NBLK 256

typedef float f32x4_ __attribute__((ext_vector_type(4)));

__device__ __forceinline__ float sigmoidf_(float x){ return 1.0f/(1.0f+expf(-x)); }

__device__ __forceinline__ float red64(float v){
  v += __shfl_xor(v, 1, 64); v += __shfl_xor(v, 2, 64);
  v += __shfl_xor(v, 4, 64); v += __shfl_xor(v, 8, 64);
  v += __shfl_xor(v, 16, 64); v += __shfl_xor(v, 32, 64);
  return v;
}
__device__ __forceinline__ float red32(float v){
  v += __shfl_xor(v, 1, 64); v += __shfl_xor(v, 2, 64);
  v += __shfl_xor(v, 4, 64); v += __shfl_xor(v, 8, 64);
  v += __shfl_xor(v, 16, 64);
  return v;
}

// 16B write-through agent-scope store (publish h cross-XCD without L2 flush)
__device__ __forceinline__ void store_wt16(float* p, float a, float b, float c, float d){
  f32x4_ v; v.x=a; v.y=b; v.z=c; v.w=d;
  asm volatile("global_store_dwordx4 %0, %1, off sc0 sc1" :: "v"(p), "v"(v) : "memory");
}

__global__ void k_rowidx(const int* __restrict__ inp, int* __restrict__ idx){
  int r = blockIdx.x*256 + threadIdx.x;
  if (r < 2048){ int l = r >> 4, b = r & 15; idx[r] = inp[b*LL + l]; }
}

template<int ACT, int KK>
__global__ __launch_bounds__(256) void k_gemm(const float* __restrict__ A, const int* __restrict__ rowidx,
                       const float* __restrict__ Bm, const float* __restrict__ bias,
                       float* __restrict__ C, int N){
  constexpr int KS = (KK==512)?9:10;
  __shared__ float As[32*KK];
  const int tid = threadIdx.x;
  const int r0 = blockIdx.x*32;
  const int c  = blockIdx.y*512 + (tid<<1);
  for (int i = tid; i < 32*KK; i += 256){
    int rr = i >> KS;
    int row = r0 + rr;
    int arow = rowidx ? rowidx[row] : row;
    int kk = i - (rr<<KS);
    As[i] = A[(size_t)arow*KK + kk];
  }
  __syncthreads();
  float2 acc[32];
  #pragma unroll
  for (int r=0;r<32;r++){ acc[r].x=0.f; acc[r].y=0.f; }
  for (int k=0;k<KK;k++){
    const float2 w = *(const float2*)(Bm + (size_t)k*N + c);
    #pragma unroll
    for (int r=0;r<32;r++){
      float a = As[(r<<KS)+k];
      acc[r].x = fmaf(a,w.x,acc[r].x);
      acc[r].y = fmaf(a,w.y,acc[r].y);
    }
  }
  const float2 bv = *(const float2*)(bias + c);
  #pragma unroll
  for (int r=0;r<32;r++){
    float x = acc[r].x + bv.x, y = acc[r].y + bv.y;
    if (ACT==1){ x = tanhf(x); y = tanhf(y); }
    *(float2*)(C + (size_t)(r0+r)*N + c) = make_float2(x,y);
  }
}

// v5: v4 MAC layouts + LDS-exchange pointwise + float4 write-through publishes
// (16 contiguous dwordx4 stores per segment instead of 64 scattered scalars).
__global__ __launch_bounds__(512,1) void k_chains(
    const float* enclast, float* H0all, float* H1all,
    const float* __restrict__ Whh0, const float* __restrict__ Whh1,
    const float* __restrict__ Wih0, const float* __restrict__ Wih1,
    const float* __restrict__ emb,
    const float* __restrict__ bih0, const float* __restrict__ bhh0,
    const float* __restrict__ bhh1, const float* __restrict__ bih1,
    int* flagsB, int* flagsA)
{
  __shared__ float w0l[12][1024];   // Whh0 cols (prologue: Wih0 scratch)
  __shared__ float w1l[12][1024];   // Whh1 cols
  __shared__ float wil[12][1024];   // Wih1 cols
  __shared__ float sumA[12][16];    // phase-A gate sums [g*4+jl][b]
  __shared__ float sumG[12][16];    // phase-B gx sums
  __shared__ float sumH[12][16];    // phase-B gh sums
  __shared__ float g0buf[12];       // gx0 + bih0 per gate-col
  __shared__ float cAh[12];         // bhh0 cols
  __shared__ float cBi[12];         // bih1 cols
  __shared__ float cBh[12];         // bhh1 cols
  const int tid  = threadIdx.x;
  const int jb   = blockIdx.x << 2;
  const int waveid = tid >> 6;
  // phase-A mapping
  const int cgA = waveid >> 2;          // 0..1
  const int bgA = waveid & 3;           // 0..3
  const int kgA = tid & 63;
  const int koffA = kgA << 2;
  const int b0A = bgA << 2;
  // phase-B mapping
  const int cgB = waveid >> 1;          // 0..3
  const int bgB = ((waveid & 1) << 1) | ((tid >> 5) & 1);
  const int kgB = tid & 31;
  const int koffB = kgB << 2;
  const int b0B = bgB << 2;
  const int mB  = cgB >> 1;             // 0: Wih1, 1: Whh1

  const bool pwA = (kgA < 8);
  const int  jlA = (cgA << 1) + (kgA & 1);
  const int  biA = (kgA >> 1) & 3;
  const int  bA  = b0A + biA;
  const bool exB = (kgB < 8);
  const int  jlB = ((cgB & 1) << 1) + (kgB & 1);
  const int  biB = (kgB >> 1) & 3;
  const int  bB  = b0B + biB;

  // ---- prologue 1: gx0 via Wih0 staged into w0l scratch ----
  {
    for (int idx = tid; idx < 1536; idx += 512){
      int g = idx >> 9, k = idx & 511;
      float4 a = *(const float4*)(Wih0 + (size_t)k*G3 + g*1024 + jb);
      w0l[g*4+0][k]=a.x; w0l[g*4+1][k]=a.y; w0l[g*4+2][k]=a.z; w0l[g*4+3][k]=a.w;
    }
    __syncthreads();
    const float* e1 = emb + EE;  // SOS row
    float ag[6];
    #pragma unroll
    for (int cl=0;cl<6;cl++) ag[cl]=0.f;
    #pragma unroll
    for (int u=0;u<2;u++){
      float4 e = *(const float4*)(e1 + u*256 + koffA);
      #pragma unroll
      for (int cl=0;cl<6;cl++){
        const int gc = ((cl>>1)<<2) + (cgA<<1) + (cl&1);
        const float4 w = *(const float4*)(&w0l[gc][u*256 + koffA]);
        float v = ag[cl];
        v=fmaf(w.x,e.x,v); v=fmaf(w.y,e.y,v); v=fmaf(w.z,e.z,v); v=fmaf(w.w,e.w,v);
        ag[cl]=v;
      }
    }
    #pragma unroll
    for (int cl=0;cl<6;cl++) ag[cl] = red64(ag[cl]);
    if (bgA == 0 && kgA < 2){
      const int parity = kgA & 1;
      const int jl = (cgA << 1) + parity;
      float v0 = parity ? ag[1] : ag[0];
      float v1 = parity ? ag[3] : ag[2];
      float v2 = parity ? ag[5] : ag[4];
      g0buf[jl]     = v0 + bih0[jb + jl];
      g0buf[4 + jl] = v1 + bih0[1024 + jb + jl];
      g0buf[8 + jl] = v2 + bih0[2048 + jb + jl];
    }
    __syncthreads();
  }

  // ---- prologue 2: stage Whh0 / Whh1 / Wih1 + bias consts ----
  for (int idx = tid; idx < 3072; idx += 512){
    int g = idx >> 10, k = idx & 1023;
    float4 a = *(const float4*)(Whh0 + (size_t)k*G3 + g*1024 + jb);
    w0l[g*4+0][k]=a.x; w0l[g*4+1][k]=a.y; w0l[g*4+2][k]=a.z; w0l[g*4+3][k]=a.w;
    float4 d = *(const float4*)(Whh1 + (size_t)k*G3 + g*1024 + jb);
    w1l[g*4+0][k]=d.x; w1l[g*4+1][k]=d.y; w1l[g*4+2][k]=d.z; w1l[g*4+3][k]=d.w;
    float4 e = *(const float4*)(Wih1 + (size_t)k*G3 + g*1024 + jb);
    wil[g*4+0][k]=e.x; wil[g*4+1][k]=e.y; wil[g*4+2][k]=e.z; wil[g*4+3][k]=e.w;
  }
  if (tid < 12){
    int g = tid >> 2, jl = tid & 3;
    cAh[tid] = bhh0[g*1024 + jb + jl];
    cBi[tid] = bih1[g*1024 + jb + jl];
    cBh[tid] = bhh1[g*1024 + jb + jl];
  }
  __syncthreads();

  const int myflag = (int)blockIdx.x * 32;
  const int pollfl = (tid & 255) * 32;

  for (int t = 0; t <= LL+1; ++t){
    // ---- wB(t) ----
    if (t >= 1){
      while (__hip_atomic_load(&flagsB[pollfl], __ATOMIC_RELAXED,
                               __HIP_MEMORY_SCOPE_AGENT) < t)
        __builtin_amdgcn_s_sleep(1);
      __syncthreads();
    }

    // ---- B(t): gx1 = h0[t-2]@Wih1 ; gh1 = h1[t-3]@Whh1 ; pointwise ----
    if (t >= 2){
      const float* hp0 = H0all + (size_t)(t-2)*(BB*HH);
      const float* hp1 = (t==2) ? enclast : (H1all + (size_t)(t-3)*(BB*HH));
      const float* hr  = mB ? hp1 : hp0;

      float accB[6][4];
      #pragma unroll
      for (int cl=0;cl<6;cl++)
        #pragma unroll
        for (int bi=0;bi<4;bi++) accB[cl][bi]=0.f;

      #pragma unroll
      for (int u=0;u<8;u++){
        float4 h4[4];
        #pragma unroll
        for (int bi=0;bi<4;bi++)
          h4[bi] = *(const float4*)(hr + (size_t)(b0B+bi)*HH + u*128 + koffB);
        #pragma unroll
        for (int cl=0;cl<6;cl++){
          const int gc = ((cl>>1)<<2) + ((cgB&1)<<1) + (cl&1);
          const float4 w = mB ? *(const float4*)(&w1l[gc][u*128 + koffB])
                              : *(const float4*)(&wil[gc][u*128 + koffB]);
          #pragma unroll
          for (int bi=0;bi<4;bi++){
            float v = accB[cl][bi];
            v=fmaf(w.x,h4[bi].x,v); v=fmaf(w.y,h4[bi].y,v);
            v=fmaf(w.z,h4[bi].z,v); v=fmaf(w.w,h4[bi].w,v);
            accB[cl][bi]=v;
          }
        }
      }
      #pragma unroll
      for (int cl=0;cl<6;cl++)
        #pragma unroll
        for (int bi=0;bi<4;bi++) accB[cl][bi] = red32(accB[cl][bi]);

      if (exB){
        float er=0.f, ez=0.f, en=0.f;
        #pragma unroll
        for (int jj=0;jj<2;jj++)
          #pragma unroll
          for (int ii=0;ii<4;ii++){
            bool sel = ((kgB&1)==jj) & (biB==ii);
            er = sel ? accB[jj][ii]   : er;
            ez = sel ? accB[2+jj][ii] : ez;
            en = sel ? accB[4+jj][ii] : en;
          }
        if (mB == 0){
          sumG[jlB][bB] = er; sumG[4+jlB][bB] = ez; sumG[8+jlB][bB] = en;
        } else {
          sumH[jlB][bB] = er; sumH[4+jlB][bB] = ez; sumH[8+jlB][bB] = en;
        }
      }
      __syncthreads();
      if (tid < 16){
        const int b = tid;
        float4 hp = *(const float4*)(hp1 + (size_t)b*HH + jb);
        float hx[4] = {hp.x, hp.y, hp.z, hp.w};
        float o[4];
        #pragma unroll
        for (int jl=0;jl<4;jl++){
          float r = sigmoidf_(sumG[jl][b]   + cBi[jl]   + sumH[jl][b]   + cBh[jl]);
          float z = sigmoidf_(sumG[4+jl][b] + cBi[4+jl] + sumH[4+jl][b] + cBh[4+jl]);
          float n = tanhf    (sumG[8+jl][b] + cBi[8+jl] + r*(sumH[8+jl][b] + cBh[8+jl]));
          o[jl] = (1.f-z)*n + z*hx[jl];
        }
        store_wt16(&H1all[(size_t)(t-2)*(BB*HH) + (size_t)b*HH + jb],
                   o[0], o[1], o[2], o[3]);
      }
    }

    // ---- sB(t) ----
    asm volatile("s_waitcnt vmcnt(0)" ::: "memory");
    __syncthreads();
    if (tid == 0)
      __hip_atomic_store(&flagsB[myflag], t+1,
                         __ATOMIC_RELAXED, __HIP_MEMORY_SCOPE_AGENT);

    // ---- wA(t) ----
    if (t >= 1){
      while (__hip_atomic_load(&flagsA[pollfl], __ATOMIC_RELAXED,
                               __HIP_MEMORY_SCOPE_AGENT) < t)
        __builtin_amdgcn_s_sleep(1);
      __syncthreads();
    }

    // ---- A(t): layer0 step t ----
    if (t < LL){
      const float* hp0 = (t==0) ? enclast : (H0all + (size_t)(t-1)*(BB*HH));

      float acc0[6][4];
      #pragma unroll
      for (int cl=0;cl<6;cl++)
        #pragma unroll
        for (int bi=0;bi<4;bi++) acc0[cl][bi]=0.f;

      #pragma unroll
      for (int u=0;u<4;u++){
        float4 h4[4];
        #pragma unroll
        for (int bi=0;bi<4;bi++)
          h4[bi] = *(const float4*)(hp0 + (size_t)(b0A+bi)*HH + u*256 + koffA);
        #pragma unroll
        for (int cl=0;cl<6;cl++){
          const int gc = ((cl>>1)<<2) + (cgA<<1) + (cl&1);
          const float4 w = *(const float4*)(&w0l[gc][u*256 + koffA]);
          #pragma unroll
          for (int bi=0;bi<4;bi++){
            float v = acc0[cl][bi];
            v=fmaf(w.x,h4[bi].x,v); v=fmaf(w.y,h4[bi].y,v);
            v=fmaf(w.z,h4[bi].z,v); v=fmaf(w.w,h4[bi].w,v);
            acc0[cl][bi]=v;
          }
        }
      }
      #pragma unroll
      for (int cl=0;cl<6;cl++)
        #pragma unroll
        for (int bi=0;bi<4;bi++) acc0[cl][bi] = red64(acc0[cl][bi]);

      if (pwA){
        float er=0.f, ez=0.f, en=0.f;
        #pragma unroll
        for (int jj=0;jj<2;jj++)
          #pragma unroll
          for (int ii=0;ii<4;ii++){
            bool sel = ((kgA&1)==jj) & (biA==ii);
            er = sel ? acc0[jj][ii]   : er;
            ez = sel ? acc0[2+jj][ii] : ez;
            en = sel ? acc0[4+jj][ii] : en;
          }
        sumA[jlA][bA] = er; sumA[4+jlA][bA] = ez; sumA[8+jlA][bA] = en;
      }
      __syncthreads();
      if (tid < 16){
        const int b = tid;
        float4 hp = *(const float4*)(hp0 + (size_t)b*HH + jb);
        float hx[4] = {hp.x, hp.y, hp.z, hp.w};
        float o[4];
        #pragma unroll
        for (int jl=0;jl<4;jl++){
          float r = sigmoidf_(g0buf[jl]   + sumA[jl][b]   + cAh[jl]);
          float z = sigmoidf_(g0buf[4+jl] + sumA[4+jl][b] + cAh[4+jl]);
          float n = tanhf    (g0buf[8+jl] + r*(sumA[8+jl][b] + cAh[8+jl]));
          o[jl] = (1.f-z)*n + z*hx[jl];
        }
        store_wt16(&H0all[(size_t)t*(BB*HH) + (size_t)b*HH + jb],
                   o[0], o[1], o[2], o[3]);
      }
    }

    // ---- sA(t) ----
    asm volatile("s_waitcnt vmcnt(0)" ::: "memory");
    __syncthreads();
    if (tid == 0)
      __hip_atomic_store(&flagsA[myflag], t+1,
                         __ATOMIC_RELAXED, __HIP_MEMORY_SCOPE_AGENT);
  }
}

__global__ __launch_bounds__(256) void k_attn(const float* __restrict__ enc, const float* __restrict__ H1,
                       float* __restrict__ ctx){
  __shared__ float h1s[8][HH];
  __shared__ float sc[8][LL];
  __shared__ float part[2][8][LL];
  const int tid = threadIdx.x;
  const int s0 = blockIdx.x*8, b = blockIdx.y;
  for (int i = tid; i < 8*HH; i += 256){
    int si = i >> 10, k = i & 1023;
    h1s[si][k] = H1[(size_t)(s0+si)*BB*HH + (size_t)b*HH + k];
  }
  __syncthreads();
  {
    const int l = tid & 127, half = tid >> 7;
    const float4* er = (const float4*)(enc + ((size_t)l*BB + b)*HH + half*512);
    float a[8];
    #pragma unroll
    for (int s=0;s<8;s++) a[s]=0.f;
    for (int q=0;q<128;q++){
      float4 e = er[q];
      #pragma unroll
      for (int s=0;s<8;s++){
        const float4 h = *(const float4*)(&h1s[s][half*512 + q*4]);
        a[s] += h.x*e.x + h.y*e.y + h.z*e.z + h.w*e.w;
      }
    }
    #pragma unroll
    for (int s=0;s<8;s++) part[half][s][l] = a[s];
  }
  __syncthreads();
  for (int p = tid; p < 1024; p += 256){
    int s = p >> 7, l = p & 127;
    sc[s][l] = (part[0][s][l] + part[1][s][l]) * 0.03125f;
  }
  __syncthreads();
  {
    int s = tid >> 5, lid = tid & 31;
    float v0 = sc[s][lid], v1 = sc[s][lid+32], v2 = sc[s][lid+64], v3 = sc[s][lid+96];
    float m = fmaxf(fmaxf(v0,v1),fmaxf(v2,v3));
    for (int off=16; off>=1; off>>=1) m = fmaxf(m, __shfl_xor(m, off, 32));
    float e0=__expf(v0-m), e1=__expf(v1-m), e2=__expf(v2-m), e3=__expf(v3-m);
    float ssum = e0+e1+e2+e3;
    for (int off=16; off>=1; off>>=1) ssum += __shfl_xor(ssum, off, 32);
    float inv = 1.0f/ssum;
    sc[s][lid]=e0*inv; sc[s][lid+32]=e1*inv; sc[s][lid+64]=e2*inv; sc[s][lid+96]=e3*inv;
  }
  __syncthreads();
  {
    float acc[4][8];
    #pragma unroll
    for (int q=0;q<4;q++)
      #pragma unroll
      for (int s=0;s<8;s++) acc[q][s]=0.f;
    for (int l=0;l<128;l++){
      const float* er = enc + ((size_t)l*BB + b)*HH + tid;
      float a[8];
      #pragma unroll
      for (int s=0;s<8;s++) a[s] = sc[s][l];
      #pragma unroll
      for (int q=0;q<4;q++){
        float e = er[q*256];
        #pragma unroll
        for (int s=0;s<8;s++) acc[q][s] = fmaf(a[s], e, acc[q][s]);
      }
    }
    #pragma unroll
    for (int s=0;s<8;s++)
      #pragma unroll
      for (int q=0;q<4;q++)
        ctx[(size_t)(s0+s)*BB*HH + (size_t)b*HH + tid + q*256] = acc[q][s];
  }
}

__global__ __launch_bounds__(256) void k_logit(const float* __restrict__ H1, const float* __restrict__ ctx,
                        const float* __restrict__ Wout, const float* __restrict__ bout,
                        const int* __restrict__ inp, const int* __restrict__ ts,
                        float* __restrict__ outp, float* __restrict__ bce){
  __shared__ float rbuf[256];
  const int i = blockIdx.x;
  const int b = i >> 7, t = i & 127;
  const int v = inp[b*LL + t];
  const int tid = threadIdx.x;
  const float* h1r = H1 + ((size_t)t*BB + b)*HH;
  const float* cxr = ctx + ((size_t)t*BB + b)*HH;
  float acc = 0.f;
  #pragma unroll
  for (int q=0;q<4;q++){
    int k = tid + q*256;
    acc = fmaf(h1r[k], Wout[(size_t)k*VV + v], acc);
  }
  #pragma unroll
  for (int q=0;q<4;q++){
    int k = tid + q*256;
    acc = fmaf(cxr[k], Wout[(size_t)(k+1024)*VV + v], acc);
  }
  rbuf[tid] = acc;
  __syncthreads();
  for (int s=128; s>0; s>>=1){
    if (tid < s) rbuf[tid] += rbuf[tid+s];
    __syncthreads();
  }
  if (tid==0){
    float logit = rbuf[0] + bout[v];
    float p = 1.0f/(1.0f + expf(-logit));
    outp[b*LL + t] = p;
    float pc = fminf(fmaxf(p, 1e-12f), 1.0f - 1e-7f);
    float tg = (float)ts[0];
    bce[i] = -(tg*logf(pc) + (1.0f-tg)*log1pf(-pc));
  }
}

__global__ void k_loss(const float* __restrict__ bce, float* __restrict__ out0){
  __shared__ float rbuf[256];
  int tid = threadIdx.x;
  float s = 0.f;
  for (int i = tid; i < 2048; i += 256) s += bce[i];
  rbuf[tid] = s; __syncthreads();
  for (int st=128; st>0; st>>=1){
    if (tid<st) rbuf[tid]+=rbuf[tid+st];
    __syncthreads();
  }
  if (tid==0) out0[0] = rbuf[0] * (1.0f/(2048.0f*16.0f));
}

extern "C" void kernel_launch(void* const* d_in, const int* in_sizes, int n_in,
                              void* d_out, int out_size, void* d_ws, size_t ws_size,
                              hipStream_t stream){
  (void)in_sizes; (void)n_in; (void)out_size; (void)ws_size;
  const int*   inp   = (const int*)d_in[0];
  const int*   ts    = (const int*)d_in[2];
  const float* emb   = (const float*)d_in[3];
  const float* encW  = (const float*)d_in[4];
  const float* encb  = (const float*)d_in[5];
  const float* Wih0  = (const float*)d_in[6];
  const float* Whh0  = (const float*)d_in[7];
  const float* bih0  = (const float*)d_in[8];
  const float* bhh0  = (const float*)d_in[9];
  const float* Wih1  = (const float*)d_in[10];
  const float* Whh1  = (const float*)d_in[11];
  const float* bih1  = (const float*)d_in[12];
  const float* bhh1  = (const float*)d_in[13];
  const float* Wout  = (const float*)d_in[14];
  const float* bout  = (const float*)d_in[15];
  float* out = (float*)d_out;

  float* ws      = (float*)d_ws;
  float* enc_out = ws;
  float* H0      = enc_out + 2097152;
  float* H1      = H0 + 2097152;
  float* GX1     = H1 + 2097152;     // unused hole (layout kept stable)
  float* CTX     = GX1 + 6291456;
  float* gx0     = CTX + 2097152;    // unused hole
  float* bceb    = gx0 + 3072;
  int*   rowidx  = (int*)(bceb + 2048);
  int*   flagsB  = rowidx + 2048;    // 256 lines x 32 ints
  int*   flagsA  = flagsB + 256*32;  // 256 lines x 32 ints

  hipMemsetAsync(flagsB, 0, 512*32*sizeof(int), stream);
  k_rowidx<<<8,256,0,stream>>>(inp, rowidx);
  k_gemm<1,512><<<dim3(64,2),256,0,stream>>>(emb, rowidx, encW, encb, enc_out, HH);

  const float* enclast = enc_out + (size_t)127*BB*HH;

  k_chains<<<NBLK,512,0,stream>>>(enclast, H0, H1, Whh0, Whh1, Wih0, Wih1, emb,
                                  bih0, bhh0, bhh1, bih1, flagsB, flagsA);
  k_attn<<<dim3(16,16),256,0,stream>>>(enc_out, H1, CTX);
  k_logit<<<2048,256,0,stream>>>(H1, CTX, Wout, bout, inp, ts, out+1, bceb);
  k_loss<<<1,256,0,stream>>>(bceb, out);
}

// Round 13
// 2069.605 us; speedup vs baseline: 1.1207x; 1.1207x over previous
//
#include <hip/hip_runtime.h>
#include <math.h>

#define BB 16
#define LL 128
#define HH 1024
#define EE 512
#define VV 32000
#define G3 3072
#define NBLK 256

__device__ __forceinline__ float sigmoidf_(float x){ return 1.0f/(1.0f+expf(-x)); }

__device__ __forceinline__ float red64(float v){
  v += __shfl_xor(v, 1, 64); v += __shfl_xor(v, 2, 64);
  v += __shfl_xor(v, 4, 64); v += __shfl_xor(v, 8, 64);
  v += __shfl_xor(v, 16, 64); v += __shfl_xor(v, 32, 64);
  return v;
}
__device__ __forceinline__ float red32(float v){
  v += __shfl_xor(v, 1, 64); v += __shfl_xor(v, 2, 64);
  v += __shfl_xor(v, 4, 64); v += __shfl_xor(v, 8, 64);
  v += __shfl_xor(v, 16, 64);
  return v;
}

__global__ void k_rowidx(const int* __restrict__ inp, int* __restrict__ idx){
  int r = blockIdx.x*256 + threadIdx.x;
  if (r < 2048){ int l = r >> 4, b = r & 15; idx[r] = inp[b*LL + l]; }
}

template<int ACT, int KK>
__global__ __launch_bounds__(256) void k_gemm(const float* __restrict__ A, const int* __restrict__ rowidx,
                       const float* __restrict__ Bm, const float* __restrict__ bias,
                       float* __restrict__ C, int N){
  constexpr int KS = (KK==512)?9:10;
  __shared__ float As[32*KK];
  const int tid = threadIdx.x;
  const int r0 = blockIdx.x*32;
  const int c  = blockIdx.y*512 + (tid<<1);
  for (int i = tid; i < 32*KK; i += 256){
    int rr = i >> KS;
    int row = r0 + rr;
    int arow = rowidx ? rowidx[row] : row;
    int kk = i - (rr<<KS);
    As[i] = A[(size_t)arow*KK + kk];
  }
  __syncthreads();
  float2 acc[32];
  #pragma unroll
  for (int r=0;r<32;r++){ acc[r].x=0.f; acc[r].y=0.f; }
  for (int k=0;k<KK;k++){
    const float2 w = *(const float2*)(Bm + (size_t)k*N + c);
    #pragma unroll
    for (int r=0;r<32;r++){
      float a = As[(r<<KS)+k];
      acc[r].x = fmaf(a,w.x,acc[r].x);
      acc[r].y = fmaf(a,w.y,acc[r].y);
    }
  }
  const float2 bv = *(const float2*)(bias + c);
  #pragma unroll
  for (int r=0;r<32;r++){
    float x = acc[r].x + bv.x, y = acc[r].y + bv.y;
    if (ACT==1){ x = tanhf(x); y = tanhf(y); }
    *(float2*)(C + (size_t)(r0+r)*N + c) = make_float2(x,y);
  }
}

// v7: R10's v4 compute phases, SINGLE barrier per round (lag-1 layer1),
// aggregator folded into block 0 (grid = 256, no co-residency hazard).
// Round t (0..128): [wait(t)] -> B(t): gx1=h0[t-1]@Wih1, layer1 step t-1
// -> A(t): layer0 step t -> drain + post flag(t+1).
__global__ __launch_bounds__(512,1) void k_chains(
    const float* enclast, float* H0all, float* H1all,
    const float* __restrict__ Whh0, const float* __restrict__ Whh1,
    const float* __restrict__ Wih0, const float* __restrict__ Wih1,
    const float* __restrict__ emb,
    const float* __restrict__ bih0, const float* __restrict__ bhh0,
    const float* __restrict__ bhh1, const float* __restrict__ bih1,
    int* flags, int* go)
{
  __shared__ float w0l[12][1024];   // Whh0 cols (prologue: Wih0 scratch)
  __shared__ float w1l[12][1024];   // Whh1 cols
  __shared__ float wil[12][1024];   // Wih1 cols
  __shared__ float gxbuf[16*12];    // phase-B gx exchange
  const int tid  = threadIdx.x;
  const int jb   = blockIdx.x << 2;
  const int waveid = tid >> 6;
  // phase-A mapping
  const int cgA = waveid >> 2;          // 0..1
  const int bgA = waveid & 3;           // 0..3
  const int kgA = tid & 63;
  const int koffA = kgA << 2;
  const int b0A = bgA << 2;
  // phase-B mapping
  const int cgB = waveid >> 1;          // 0..3
  const int bgB = ((waveid & 1) << 1) | ((tid >> 5) & 1);
  const int kgB = tid & 31;
  const int koffB = kgB << 2;
  const int b0B = bgB << 2;
  const int mB  = cgB >> 1;             // 0: Wih1, 1: Whh1

  const bool pwA = (kgA < 8);
  const int  jlA = (cgA << 1) + (kgA & 1);
  const int  jpA = jb + jlA;
  const int  biA = (kgA >> 1) & 3;
  const int  bA  = b0A + biA;
  const bool pwB = (cgB >= 2) && (kgB < 8);
  const int  jlB = ((cgB & 1) << 1) + (kgB & 1);
  const int  jpB = jb + jlB;
  const int  biB = (kgB >> 1) & 3;
  const int  bB  = b0B + biB;

  // ---- prologue 1: gx0 via Wih0 staged into w0l scratch ----
  float g0r=0.f, g0z=0.f, g0n=0.f;
  {
    for (int idx = tid; idx < 1536; idx += 512){
      int g = idx >> 9, k = idx & 511;
      float4 a = *(const float4*)(Wih0 + (size_t)k*G3 + g*1024 + jb);
      w0l[g*4+0][k]=a.x; w0l[g*4+1][k]=a.y; w0l[g*4+2][k]=a.z; w0l[g*4+3][k]=a.w;
    }
    __syncthreads();
    const float* e1 = emb + EE;  // SOS row
    float ag[6];
    #pragma unroll
    for (int cl=0;cl<6;cl++) ag[cl]=0.f;
    #pragma unroll
    for (int u=0;u<2;u++){
      float4 e = *(const float4*)(e1 + u*256 + koffA);
      #pragma unroll
      for (int cl=0;cl<6;cl++){
        const int gc = ((cl>>1)<<2) + (cgA<<1) + (cl&1);
        const float4 w = *(const float4*)(&w0l[gc][u*256 + koffA]);
        float v = ag[cl];
        v=fmaf(w.x,e.x,v); v=fmaf(w.y,e.y,v); v=fmaf(w.z,e.z,v); v=fmaf(w.w,e.w,v);
        ag[cl]=v;
      }
    }
    #pragma unroll
    for (int cl=0;cl<6;cl++) ag[cl] = red64(ag[cl]);
    if (pwA){
      const int jj = kgA & 1;
      g0r = (jj ? ag[1] : ag[0]) + bih0[jpA];
      g0z = (jj ? ag[3] : ag[2]) + bih0[1024+jpA];
      g0n = (jj ? ag[5] : ag[4]) + bih0[2048+jpA];
    }
    __syncthreads();
  }

  // ---- prologue 2: stage Whh0 / Whh1 / Wih1 ----
  for (int idx = tid; idx < 3072; idx += 512){
    int g = idx >> 10, k = idx & 1023;
    float4 a = *(const float4*)(Whh0 + (size_t)k*G3 + g*1024 + jb);
    w0l[g*4+0][k]=a.x; w0l[g*4+1][k]=a.y; w0l[g*4+2][k]=a.z; w0l[g*4+3][k]=a.w;
    float4 d = *(const float4*)(Whh1 + (size_t)k*G3 + g*1024 + jb);
    w1l[g*4+0][k]=d.x; w1l[g*4+1][k]=d.y; w1l[g*4+2][k]=d.z; w1l[g*4+3][k]=d.w;
    float4 e = *(const float4*)(Wih1 + (size_t)k*G3 + g*1024 + jb);
    wil[g*4+0][k]=e.x; wil[g*4+1][k]=e.y; wil[g*4+2][k]=e.z; wil[g*4+3][k]=e.w;
  }
  float b0rA=0.f,b0zA=0.f,b0nA=0.f;
  if (pwA){ b0rA = bhh0[jpA]; b0zA = bhh0[1024+jpA]; b0nA = bhh0[2048+jpA]; }
  float birB=0.f,bizB=0.f,binB=0.f,b1rB=0.f,b1zB=0.f,b1nB=0.f;
  if (pwB){
    birB = bih1[jpB]; bizB = bih1[1024+jpB]; binB = bih1[2048+jpB];
    b1rB = bhh1[jpB]; b1zB = bhh1[1024+jpB]; b1nB = bhh1[2048+jpB];
  }
  __syncthreads();

  const int myflag = (int)blockIdx.x * 32;

  for (int t = 0; t <= LL; ++t){
    // ---- wait(t): block 0 aggregates; workers poll the single go line ----
    if (t >= 1){
      if (blockIdx.x == 0){
        if (tid < 256){
          while (__hip_atomic_load(&flags[tid*32], __ATOMIC_RELAXED,
                                   __HIP_MEMORY_SCOPE_AGENT) < t)
            __builtin_amdgcn_s_sleep(1);
        }
        __syncthreads();
        if (tid == 0)
          __hip_atomic_store(go, t, __ATOMIC_RELAXED, __HIP_MEMORY_SCOPE_AGENT);
      } else {
        if (tid == 0){
          while (__hip_atomic_load(go, __ATOMIC_RELAXED,
                                   __HIP_MEMORY_SCOPE_AGENT) < t)
            __builtin_amdgcn_s_sleep(1);
        }
        __syncthreads();
      }
    }

    // ---- B(t): gx1 = h0[t-1]@Wih1 ; layer1 step t-1 ----
    if (t >= 1){
      const float* hp0 = H0all + (size_t)(t-1)*(BB*HH);
      const float* hp1 = (t==1) ? enclast : (H1all + (size_t)(t-2)*(BB*HH));
      const float* hr  = mB ? hp1 : hp0;
      float hprev1 = 0.f;
      if (pwB) hprev1 = hp1[(size_t)bB*HH + jpB];

      float accB[6][4];
      #pragma unroll
      for (int cl=0;cl<6;cl++)
        #pragma unroll
        for (int bi=0;bi<4;bi++) accB[cl][bi]=0.f;

      #pragma unroll
      for (int u=0;u<8;u++){
        float4 h4[4];
        #pragma unroll
        for (int bi=0;bi<4;bi++)
          h4[bi] = *(const float4*)(hr + (size_t)(b0B+bi)*HH + u*128 + koffB);
        #pragma unroll
        for (int cl=0;cl<6;cl++){
          const int gc = ((cl>>1)<<2) + ((cgB&1)<<1) + (cl&1);
          const float4 w = mB ? *(const float4*)(&w1l[gc][u*128 + koffB])
                              : *(const float4*)(&wil[gc][u*128 + koffB]);
          #pragma unroll
          for (int bi=0;bi<4;bi++){
            float v = accB[cl][bi];
            v=fmaf(w.x,h4[bi].x,v); v=fmaf(w.y,h4[bi].y,v);
            v=fmaf(w.z,h4[bi].z,v); v=fmaf(w.w,h4[bi].w,v);
            accB[cl][bi]=v;
          }
        }
      }
      #pragma unroll
      for (int cl=0;cl<6;cl++)
        #pragma unroll
        for (int bi=0;bi<4;bi++) accB[cl][bi] = red32(accB[cl][bi]);

      // exchange: Wih1 waves publish gx sums
      if (mB == 0){
        #pragma unroll
        for (int cl=0;cl<6;cl++){
          if (kgB == cl){
            const int g = cl >> 1;
            const int jl = ((cgB&1)<<1) + (cl&1);
            #pragma unroll
            for (int bi=0;bi<4;bi++)
              gxbuf[(b0B+bi)*12 + g*4 + jl] = accB[cl][bi];
          }
        }
      }
      __syncthreads();
      if (pwB){
        float ghr=0.f, ghz=0.f, ghn=0.f;
        #pragma unroll
        for (int jj=0;jj<2;jj++)
          #pragma unroll
          for (int ii=0;ii<4;ii++){
            bool sel = ((kgB&1)==jj) & (biB==ii);
            ghr = sel ? accB[jj][ii]   : ghr;
            ghz = sel ? accB[2+jj][ii] : ghz;
            ghn = sel ? accB[4+jj][ii] : ghn;
          }
        float gxr = gxbuf[bB*12 + 0*4 + jlB];
        float gxz = gxbuf[bB*12 + 1*4 + jlB];
        float gxn = gxbuf[bB*12 + 2*4 + jlB];
        float r = sigmoidf_(gxr + birB + ghr + b1rB);
        float z = sigmoidf_(gxz + bizB + ghz + b1zB);
        float n = tanhf    (gxn + binB + r*(ghn + b1nB));
        float hnew = (1.f-z)*n + z*hprev1;
        __hip_atomic_store((int*)&H1all[(size_t)(t-1)*(BB*HH) + (size_t)bB*HH + jpB],
                           __float_as_int(hnew),
                           __ATOMIC_RELAXED, __HIP_MEMORY_SCOPE_AGENT);
      }
    }

    // ---- A(t): layer0 step t ----
    if (t < LL){
      const float* hp0 = (t==0) ? enclast : (H0all + (size_t)(t-1)*(BB*HH));
      float hprev0 = 0.f;
      if (pwA) hprev0 = hp0[(size_t)bA*HH + jpA];

      float acc0[6][4];
      #pragma unroll
      for (int cl=0;cl<6;cl++)
        #pragma unroll
        for (int bi=0;bi<4;bi++) acc0[cl][bi]=0.f;

      #pragma unroll
      for (int u=0;u<4;u++){
        float4 h4[4];
        #pragma unroll
        for (int bi=0;bi<4;bi++)
          h4[bi] = *(const float4*)(hp0 + (size_t)(b0A+bi)*HH + u*256 + koffA);
        #pragma unroll
        for (int cl=0;cl<6;cl++){
          const int gc = ((cl>>1)<<2) + (cgA<<1) + (cl&1);
          const float4 w = *(const float4*)(&w0l[gc][u*256 + koffA]);
          #pragma unroll
          for (int bi=0;bi<4;bi++){
            float v = acc0[cl][bi];
            v=fmaf(w.x,h4[bi].x,v); v=fmaf(w.y,h4[bi].y,v);
            v=fmaf(w.z,h4[bi].z,v); v=fmaf(w.w,h4[bi].w,v);
            acc0[cl][bi]=v;
          }
        }
      }
      #pragma unroll
      for (int cl=0;cl<6;cl++)
        #pragma unroll
        for (int bi=0;bi<4;bi++) acc0[cl][bi] = red64(acc0[cl][bi]);

      if (pwA){
        float ghr=0.f, ghz=0.f, ghn=0.f;
        #pragma unroll
        for (int jj=0;jj<2;jj++)
          #pragma unroll
          for (int ii=0;ii<4;ii++){
            bool sel = ((kgA&1)==jj) & (biA==ii);
            ghr = sel ? acc0[jj][ii]   : ghr;
            ghz = sel ? acc0[2+jj][ii] : ghz;
            ghn = sel ? acc0[4+jj][ii] : ghn;
          }
        float r = sigmoidf_(g0r + ghr + b0rA);
        float z = sigmoidf_(g0z + ghz + b0zA);
        float n = tanhf    (g0n + r*(ghn + b0nA));
        float hnew = (1.f-z)*n + z*hprev0;
        __hip_atomic_store((int*)&H0all[(size_t)t*(BB*HH) + (size_t)bA*HH + jpA],
                           __float_as_int(hnew),
                           __ATOMIC_RELAXED, __HIP_MEMORY_SCOPE_AGENT);
      }
    }

    // ---- publish round completion ----
    if (t < LL){
      asm volatile("s_waitcnt vmcnt(0)" ::: "memory");
      __syncthreads();
      if (tid == 0)
        __hip_atomic_store(&flags[myflag], t+1,
                           __ATOMIC_RELAXED, __HIP_MEMORY_SCOPE_AGENT);
    }
  }
}

__global__ __launch_bounds__(256) void k_attn(const float* __restrict__ enc, const float* __restrict__ H1,
                       float* __restrict__ ctx){
  __shared__ float h1s[8][HH];
  __shared__ float sc[8][LL];
  __shared__ float part[2][8][LL];
  const int tid = threadIdx.x;
  const int s0 = blockIdx.x*8, b = blockIdx.y;
  for (int i = tid; i < 8*HH; i += 256){
    int si = i >> 10, k = i & 1023;
    h1s[si][k] = H1[(size_t)(s0+si)*BB*HH + (size_t)b*HH + k];
  }
  __syncthreads();
  {
    const int l = tid & 127, half = tid >> 7;
    const float4* er = (const float4*)(enc + ((size_t)l*BB + b)*HH + half*512);
    float a[8];
    #pragma unroll
    for (int s=0;s<8;s++) a[s]=0.f;
    for (int q=0;q<128;q++){
      float4 e = er[q];
      #pragma unroll
      for (int s=0;s<8;s++){
        const float4 h = *(const float4*)(&h1s[s][half*512 + q*4]);
        a[s] += h.x*e.x + h.y*e.y + h.z*e.z + h.w*e.w;
      }
    }
    #pragma unroll
    for (int s=0;s<8;s++) part[half][s][l] = a[s];
  }
  __syncthreads();
  for (int p = tid; p < 1024; p += 256){
    int s = p >> 7, l = p & 127;
    sc[s][l] = (part[0][s][l] + part[1][s][l]) * 0.03125f;
  }
  __syncthreads();
  {
    int s = tid >> 5, lid = tid & 31;
    float v0 = sc[s][lid], v1 = sc[s][lid+32], v2 = sc[s][lid+64], v3 = sc[s][lid+96];
    float m = fmaxf(fmaxf(v0,v1),fmaxf(v2,v3));
    for (int off=16; off>=1; off>>=1) m = fmaxf(m, __shfl_xor(m, off, 32));
    float e0=__expf(v0-m), e1=__expf(v1-m), e2=__expf(v2-m), e3=__expf(v3-m);
    float ssum = e0+e1+e2+e3;
    for (int off=16; off>=1; off>>=1) ssum += __shfl_xor(ssum, off, 32);
    float inv = 1.0f/ssum;
    sc[s][lid]=e0*inv; sc[s][lid+32]=e1*inv; sc[s][lid+64]=e2*inv; sc[s][lid+96]=e3*inv;
  }
  __syncthreads();
  {
    float acc[4][8];
    #pragma unroll
    for (int q=0;q<4;q++)
      #pragma unroll
      for (int s=0;s<8;s++) acc[q][s]=0.f;
    for (int l=0;l<128;l++){
      const float* er = enc + ((size_t)l*BB + b)*HH + tid;
      float a[8];
      #pragma unroll
      for (int s=0;s<8;s++) a[s] = sc[s][l];
      #pragma unroll
      for (int q=0;q<4;q++){
        float e = er[q*256];
        #pragma unroll
        for (int s=0;s<8;s++) acc[q][s] = fmaf(a[s], e, acc[q][s]);
      }
    }
    #pragma unroll
    for (int s=0;s<8;s++)
      #pragma unroll
      for (int q=0;q<4;q++)
        ctx[(size_t)(s0+s)*BB*HH + (size_t)b*HH + tid + q*256] = acc[q][s];
  }
}

__global__ __launch_bounds__(256) void k_logit(const float* __restrict__ H1, const float* __restrict__ ctx,
                        const float* __restrict__ Wout, const float* __restrict__ bout,
                        const int* __restrict__ inp, const int* __restrict__ ts,
                        float* __restrict__ outp, float* __restrict__ bce){
  __shared__ float rbuf[256];
  const int i = blockIdx.x;
  const int b = i >> 7, t = i & 127;
  const int v = inp[b*LL + t];
  const int tid = threadIdx.x;
  const float* h1r = H1 + ((size_t)t*BB + b)*HH;
  const float* cxr = ctx + ((size_t)t*BB + b)*HH;
  float acc = 0.f;
  #pragma unroll
  for (int q=0;q<4;q++){
    int k = tid + q*256;
    acc = fmaf(h1r[k], Wout[(size_t)k*VV + v], acc);
  }
  #pragma unroll
  for (int q=0;q<4;q++){
    int k = tid + q*256;
    acc = fmaf(cxr[k], Wout[(size_t)(k+1024)*VV + v], acc);
  }
  rbuf[tid] = acc;
  __syncthreads();
  for (int s=128; s>0; s>>=1){
    if (tid < s) rbuf[tid] += rbuf[tid+s];
    __syncthreads();
  }
  if (tid==0){
    float logit = rbuf[0] + bout[v];
    float p = 1.0f/(1.0f + expf(-logit));
    outp[b*LL + t] = p;
    float pc = fminf(fmaxf(p, 1e-12f), 1.0f - 1e-7f);
    float tg = (float)ts[0];
    bce[i] = -(tg*logf(pc) + (1.0f-tg)*log1pf(-pc));
  }
}

__global__ void k_loss(const float* __restrict__ bce, float* __restrict__ out0){
  __shared__ float rbuf[256];
  int tid = threadIdx.x;
  float s = 0.f;
  for (int i = tid; i < 2048; i += 256) s += bce[i];
  rbuf[tid] = s; __syncthreads();
  for (int st=128; st>0; st>>=1){
    if (tid<st) rbuf[tid]+=rbuf[tid+st];
    __syncthreads();
  }
  if (tid==0) out0[0] = rbuf[0] * (1.0f/(2048.0f*16.0f));
}

extern "C" void kernel_launch(void* const* d_in, const int* in_sizes, int n_in,
                              void* d_out, int out_size, void* d_ws, size_t ws_size,
                              hipStream_t stream){
  (void)in_sizes; (void)n_in; (void)out_size; (void)ws_size;
  const int*   inp   = (const int*)d_in[0];
  const int*   ts    = (const int*)d_in[2];
  const float* emb   = (const float*)d_in[3];
  const float* encW  = (const float*)d_in[4];
  const float* encb  = (const float*)d_in[5];
  const float* Wih0  = (const float*)d_in[6];
  const float* Whh0  = (const float*)d_in[7];
  const float* bih0  = (const float*)d_in[8];
  const float* bhh0  = (const float*)d_in[9];
  const float* Wih1  = (const float*)d_in[10];
  const float* Whh1  = (const float*)d_in[11];
  const float* bih1  = (const float*)d_in[12];
  const float* bhh1  = (const float*)d_in[13];
  const float* Wout  = (const float*)d_in[14];
  const float* bout  = (const float*)d_in[15];
  float* out = (float*)d_out;

  float* ws      = (float*)d_ws;
  float* enc_out = ws;
  float* H0      = enc_out + 2097152;
  float* H1      = H0 + 2097152;
  float* GX1     = H1 + 2097152;     // unused hole (layout kept stable)
  float* CTX     = GX1 + 6291456;
  float* gx0     = CTX + 2097152;    // unused hole
  float* bceb    = gx0 + 3072;
  int*   rowidx  = (int*)(bceb + 2048);
  int*   flags   = rowidx + 2048;    // 256 lines x 32 ints
  int*   go      = flags + 256*32;   // 1 line

  hipMemsetAsync(flags, 0, (256*32 + 32)*sizeof(int), stream);
  k_rowidx<<<8,256,0,stream>>>(inp, rowidx);
  k_gemm<1,512><<<dim3(64,2),256,0,stream>>>(emb, rowidx, encW, encb, enc_out, HH);

  const float* enclast = enc_out + (size_t)127*BB*HH;

  k_chains<<<NBLK,512,0,stream>>>(enclast, H0, H1, Whh0, Whh1, Wih0, Wih1, emb,
                                  bih0, bhh0, bhh1, bih1, flags, go);
  k_attn<<<dim3(16,16),256,0,stream>>>(enc_out, H1, CTX);
  k_logit<<<2048,256,0,stream>>>(H1, CTX, Wout, bout, inp, ts, out+1, bceb);
  k_loss<<<1,256,0,stream>>>(bceb, out);
}